// Round 2
// baseline (1110.438 us; speedup 1.0000x reference)
//
#include <hip/hip_runtime.h>

#define DIM 64
#define NGRAPH 128
#define GATTR 4
#define BN_EPS 1e-5f

// ---------------- CSR build ----------------

__global__ void k_count(const int* __restrict__ dst, int* __restrict__ cnt, int E) {
    int e = blockIdx.x * blockDim.x + threadIdx.x;
    if (e < E) atomicAdd(&cnt[dst[e]], 1);
}

__global__ __launch_bounds__(1024) void k_scan(const int* __restrict__ cnt,
                                               int* __restrict__ row_ptr,
                                               int* __restrict__ wp,
                                               int n, int E) {
    __shared__ int sums[1024];
    int tid = threadIdx.x;
    int chunk = (n + 1023) >> 10;
    int start = tid * chunk;
    int end = min(start + chunk, n);
    int s = 0;
    for (int i = start; i < end; ++i) s += cnt[i];
    sums[tid] = s;
    __syncthreads();
    // Hillis-Steele inclusive scan over 1024 partials
    for (int off = 1; off < 1024; off <<= 1) {
        int v = (tid >= off) ? sums[tid - off] : 0;
        __syncthreads();
        sums[tid] += v;
        __syncthreads();
    }
    int excl = (tid == 0) ? 0 : sums[tid - 1];
    for (int i = start; i < end; ++i) {
        row_ptr[i] = excl;
        wp[i] = excl;
        excl += cnt[i];
    }
    if (tid == 0) row_ptr[n] = E;
}

__global__ void k_scatter(const int* __restrict__ src, const int* __restrict__ dst,
                          int* __restrict__ wp, int* __restrict__ col, int E) {
    int e = blockIdx.x * blockDim.x + threadIdx.x;
    if (e < E) {
        int p = atomicAdd(&wp[dst[e]], 1);
        col[p] = src[e];
    }
}

// ---------------- mean aggregation: one wave per node, lane = dim ----------------

__global__ __launch_bounds__(256) void k_agg(const float* __restrict__ h,
                                             const int* __restrict__ row_ptr,
                                             const int* __restrict__ col,
                                             float* __restrict__ agg, int n) {
    int wid = (blockIdx.x * blockDim.x + threadIdx.x) >> 6;
    int lane = threadIdx.x & 63;
    if (wid >= n) return;
    int beg = row_ptr[wid], end = row_ptr[wid + 1];
    float acc = 0.f;
    for (int j = beg; j < end; ++j) {
        int s = col[j];
        acc += h[(size_t)s * DIM + lane];
    }
    float c = (float)(end - beg);
    agg[(size_t)wid * DIM + lane] = acc / fmaxf(c, 1.0f);
}

// ---------------- fused linear (agg@Wl + bl + h@Wr) + BN(eval) + ReLU ----------------
// 64-node tile per block, 256 threads; Wl/Wr/A/H staged in LDS (64 KiB -> 2 blocks/CU).

__global__ __launch_bounds__(256) void k_xform(const float* __restrict__ agg,
                                               const float* __restrict__ h,
                                               const float* __restrict__ Wl,
                                               const float* __restrict__ bl,
                                               const float* __restrict__ Wr,
                                               const float* __restrict__ bng,
                                               const float* __restrict__ bnb,
                                               const float* __restrict__ bnm,
                                               const float* __restrict__ bnv,
                                               float* __restrict__ out, int n) {
    __shared__ float sWl[64 * 64];
    __shared__ float sWr[64 * 64];
    __shared__ float sA[64 * 64];
    __shared__ float sH[64 * 64];
    int tid = threadIdx.x;
    int base = blockIdx.x * 64;
    int rows = min(64, n - base);

    const float4* Wl4 = (const float4*)Wl;
    const float4* Wr4 = (const float4*)Wr;
    float4* sWl4 = (float4*)sWl;
    float4* sWr4 = (float4*)sWr;
    const float4* A4 = (const float4*)(agg + (size_t)base * DIM);
    const float4* H4 = (const float4*)(h + (size_t)base * DIM);
    float4* sA4 = (float4*)sA;
    float4* sH4 = (float4*)sH;
    for (int i = tid; i < 64 * 64 / 4; i += 256) {
        sWl4[i] = Wl4[i];
        sWr4[i] = Wr4[i];
        int row = i >> 4;  // (i*4)/64
        float4 va = {0.f, 0.f, 0.f, 0.f}, vh = {0.f, 0.f, 0.f, 0.f};
        if (row < rows) { va = A4[i]; vh = H4[i]; }
        sA4[i] = va;
        sH4[i] = vh;
    }
    __syncthreads();

    int d = tid & 63;   // output dim (lane)
    int nq = tid >> 6;  // wave id in block: handles nodes nq, nq+4, ..., nq+60
    float acc[16];
#pragma unroll
    for (int i = 0; i < 16; ++i) acc[i] = 0.f;

    for (int k = 0; k < 64; k += 4) {
        float wl0 = sWl[(k + 0) * 64 + d];
        float wl1 = sWl[(k + 1) * 64 + d];
        float wl2 = sWl[(k + 2) * 64 + d];
        float wl3 = sWl[(k + 3) * 64 + d];
        float wr0 = sWr[(k + 0) * 64 + d];
        float wr1 = sWr[(k + 1) * 64 + d];
        float wr2 = sWr[(k + 2) * 64 + d];
        float wr3 = sWr[(k + 3) * 64 + d];
#pragma unroll
        for (int i = 0; i < 16; ++i) {
            int nd = nq + 4 * i;
            const float4 a4 = *(const float4*)&sA[nd * 64 + k];  // wave-uniform -> broadcast
            const float4 h4 = *(const float4*)&sH[nd * 64 + k];
            acc[i] += a4.x * wl0 + a4.y * wl1 + a4.z * wl2 + a4.w * wl3
                    + h4.x * wr0 + h4.y * wr1 + h4.z * wr2 + h4.w * wr3;
        }
    }

    float scale = bng[d] / sqrtf(bnv[d] + BN_EPS);
    float shift = bnb[d];
    float mean = bnm[d];
    float bias = bl[d];
#pragma unroll
    for (int i = 0; i < 16; ++i) {
        int nd = nq + 4 * i;
        int node = base + nd;
        if (node < n) {
            float v = (acc[i] + bias - mean) * scale + shift;
            out[(size_t)node * DIM + d] = fmaxf(v, 0.f);
        }
    }
}

// ---------------- global mean pool (batch is sorted) ----------------

__global__ __launch_bounds__(256) void k_pool(const float* __restrict__ h,
                                              const int* __restrict__ batch,
                                              float* __restrict__ gsum,
                                              int* __restrict__ gcnt,
                                              int n, int npb) {
    __shared__ float ls[NGRAPH * DIM];  // 32 KiB
    __shared__ int lc[NGRAPH];
    int tid = threadIdx.x;
    for (int i = tid; i < NGRAPH * DIM; i += 256) ls[i] = 0.f;
    for (int i = tid; i < NGRAPH; i += 256) lc[i] = 0;
    __syncthreads();
    int start = blockIdx.x * npb;
    int end = min(start + npb, n);
    int lane = tid & 63, wv = tid >> 6;
    for (int i = start + wv; i < end; i += 4) {
        int g = batch[i];
        atomicAdd(&ls[g * DIM + lane], h[(size_t)i * DIM + lane]);
        if (lane == 0) atomicAdd(&lc[g], 1);
    }
    __syncthreads();
    // batch sorted: only graphs [gmin, gmax] are touched by this block
    int gmin = batch[start];
    int gmax = batch[end - 1];
    int span = gmax - gmin + 1;
    for (int i = tid; i < span * DIM; i += 256)
        atomicAdd(&gsum[gmin * DIM + i], ls[gmin * DIM + i]);
    for (int i = tid; i < span; i += 256)
        atomicAdd(&gcnt[gmin + i], lc[gmin + i]);
}

// ---------------- classifier head: [G,64]+[G,4] -> 32 -> 2 ----------------

__global__ __launch_bounds__(256) void k_mlp(const float* __restrict__ gsum,
                                             const int* __restrict__ gcnt,
                                             const float* __restrict__ gattr,
                                             const float* __restrict__ W1,
                                             const float* __restrict__ b1,
                                             const float* __restrict__ W2,
                                             const float* __restrict__ b2,
                                             float* __restrict__ out) {
    __shared__ float emb[NGRAPH][DIM + GATTR];  // 128 x 68
    __shared__ float hid[NGRAPH][32];
    int tid = threadIdx.x;
    for (int i = tid; i < NGRAPH * DIM; i += 256) {
        int g = i >> 6, d = i & 63;
        float c = (float)gcnt[g];
        emb[g][d] = gsum[i] / fmaxf(c, 1.0f);
    }
    for (int i = tid; i < NGRAPH * GATTR; i += 256) {
        int g = i >> 2, d = i & 3;
        emb[g][DIM + d] = gattr[i];
    }
    __syncthreads();
    for (int t = tid; t < NGRAPH * 32; t += 256) {
        int g = t >> 5, j = t & 31;
        float a = b1[j];
        for (int k = 0; k < DIM + GATTR; ++k) a += emb[g][k] * W1[k * 32 + j];
        hid[g][j] = fmaxf(a, 0.f);
    }
    __syncthreads();
    {
        int g = tid >> 1, o = tid & 1;
        float a = b2[o];
        for (int k = 0; k < 32; ++k) a += hid[g][k] * W2[k * 2 + o];
        out[g * 2 + o] = a;
    }
}

extern "C" void kernel_launch(void* const* d_in, const int* in_sizes, int n_in,
                              void* d_out, int out_size, void* d_ws, size_t ws_size,
                              hipStream_t stream) {
    const float* x = (const float*)d_in[0];
    const int* ei = (const int*)d_in[1];
    const int* batch = (const int*)d_in[2];
    const float* gattr = (const float*)d_in[3];
    const int N = in_sizes[0] / DIM;
    const int E = in_sizes[1] / 2;
    const int* src = ei;
    const int* dst = ei + E;

    const float *Wl[3], *bl[3], *Wr[3], *bg[3], *bb[3], *bm[3], *bv[3];
    for (int l = 0; l < 3; ++l) {
        int base = 4 + l * 7;
        Wl[l] = (const float*)d_in[base + 0];
        bl[l] = (const float*)d_in[base + 1];
        Wr[l] = (const float*)d_in[base + 2];
        bg[l] = (const float*)d_in[base + 3];
        bb[l] = (const float*)d_in[base + 4];
        bm[l] = (const float*)d_in[base + 5];
        bv[l] = (const float*)d_in[base + 6];
    }
    const float* W1 = (const float*)d_in[25];
    const float* b1 = (const float*)d_in[26];
    const float* W2 = (const float*)d_in[27];
    const float* b2 = (const float*)d_in[28];

    char* ws = (char*)d_ws;
    size_t off = 0;
    auto alloc = [&](size_t bytes) -> char* {
        char* p = ws + off;
        off += (bytes + 255) & ~(size_t)255;
        return p;
    };
    int* cnt = (int*)alloc((size_t)N * 4);
    int* rowptr = (int*)alloc((size_t)(N + 1) * 4);
    int* wp = (int*)alloc((size_t)N * 4);
    int* col = (int*)alloc((size_t)E * 4);
    float* aggb = (float*)alloc((size_t)N * DIM * 4);
    float* h0 = (float*)alloc((size_t)N * DIM * 4);
    float* h1 = (float*)alloc((size_t)N * DIM * 4);
    float* gsum = (float*)alloc((size_t)NGRAPH * DIM * 4);
    int* gcnt = (int*)alloc((size_t)NGRAPH * 4);
    (void)ws_size;

    hipMemsetAsync(cnt, 0, (size_t)N * 4, stream);
    hipMemsetAsync(gsum, 0, (size_t)NGRAPH * DIM * 4, stream);
    hipMemsetAsync(gcnt, 0, (size_t)NGRAPH * 4, stream);

    const int tpb = 256;
    k_count<<<(E + tpb - 1) / tpb, tpb, 0, stream>>>(dst, cnt, E);
    k_scan<<<1, 1024, 0, stream>>>(cnt, rowptr, wp, N, E);
    k_scatter<<<(E + tpb - 1) / tpb, tpb, 0, stream>>>(src, dst, wp, col, E);

    const float* hin = x;
    float* houts[3] = {h0, h1, h0};
    for (int l = 0; l < 3; ++l) {
        k_agg<<<(N * 64 + tpb - 1) / tpb, tpb, 0, stream>>>(hin, rowptr, col, aggb, N);
        k_xform<<<(N + 63) / 64, 256, 0, stream>>>(aggb, hin, Wl[l], bl[l], Wr[l],
                                                   bg[l], bb[l], bm[l], bv[l], houts[l], N);
        hin = houts[l];
    }

    const int NPB = 1024;
    k_pool<<<(N + NPB - 1) / NPB, tpb, 0, stream>>>(hin, batch, gsum, gcnt, N, NPB);
    k_mlp<<<1, tpb, 0, stream>>>(gsum, gcnt, gattr, W1, b1, W2, b2, (float*)d_out);
}

// Round 3
// 881.029 us; speedup vs baseline: 1.2604x; 1.2604x over previous
//
#include <hip/hip_runtime.h>

#define DIM 64
#define NGRAPH 128
#define GATTR 4
#define BN_EPS 1e-5f
#define SCAN_CHUNK 4096  // 256 threads x 16 elems

// ---------------- CSR build ----------------

__global__ void k_count(const int* __restrict__ dst, int* __restrict__ cnt, int E) {
    int e = blockIdx.x * blockDim.x + threadIdx.x;
    if (e < E) atomicAdd(&cnt[dst[e]], 1);
}

// Stage 1: per-block local exclusive scan (4096 elems) + block total
__global__ __launch_bounds__(256) void k_scan1(const int* __restrict__ cnt,
                                               int* __restrict__ rowptr,
                                               int* __restrict__ partials, int n) {
    __shared__ int ws[256];
    int tid = threadIdx.x;
    int base = blockIdx.x * SCAN_CHUNK + tid * 16;
    int v[16];
    int s = 0;
#pragma unroll
    for (int i = 0; i < 16; ++i) {
        int idx = base + i;
        v[i] = (idx < n) ? cnt[idx] : 0;
        s += v[i];
    }
    ws[tid] = s;
    __syncthreads();
    for (int off = 1; off < 256; off <<= 1) {
        int t = (tid >= off) ? ws[tid - off] : 0;
        __syncthreads();
        ws[tid] += t;
        __syncthreads();
    }
    int excl = (tid == 0) ? 0 : ws[tid - 1];
    if (tid == 255) partials[blockIdx.x] = ws[255];
#pragma unroll
    for (int i = 0; i < 16; ++i) {
        int idx = base + i;
        if (idx < n) rowptr[idx] = excl;
        excl += v[i];
    }
}

// Stage 2: exclusive scan of block totals (nb <= 256)
__global__ __launch_bounds__(256) void k_scan2(int* __restrict__ partials, int nb) {
    __shared__ int ws[256];
    int tid = threadIdx.x;
    int orig = (tid < nb) ? partials[tid] : 0;
    ws[tid] = orig;
    __syncthreads();
    for (int off = 1; off < 256; off <<= 1) {
        int t = (tid >= off) ? ws[tid - off] : 0;
        __syncthreads();
        ws[tid] += t;
        __syncthreads();
    }
    if (tid < nb) partials[tid] = ws[tid] - orig;  // exclusive
}

// Stage 3: add block offsets, fan out to rowptr and wp
__global__ __launch_bounds__(256) void k_scan3(int* __restrict__ rowptr,
                                               int* __restrict__ wp,
                                               const int* __restrict__ partials,
                                               int n, int E) {
    int base = blockIdx.x * SCAN_CHUNK;
    int off = partials[blockIdx.x];
    for (int i = threadIdx.x; i < SCAN_CHUNK; i += 256) {
        int idx = base + i;
        if (idx < n) {
            int v = rowptr[idx] + off;
            rowptr[idx] = v;
            wp[idx] = v;
        }
    }
    if (blockIdx.x == 0 && threadIdx.x == 0) rowptr[n] = E;
}

__global__ void k_scatter(const int* __restrict__ src, const int* __restrict__ dst,
                          int* __restrict__ wp, int* __restrict__ col, int E) {
    int e = blockIdx.x * blockDim.x + threadIdx.x;
    if (e < E) {
        int p = atomicAdd(&wp[dst[e]], 1);
        col[p] = src[e];
    }
}

// ---------------- mean aggregation: one wave per node, lane = dim ----------------

__global__ __launch_bounds__(256) void k_agg(const float* __restrict__ h,
                                             const int* __restrict__ row_ptr,
                                             const int* __restrict__ col,
                                             float* __restrict__ agg, int n) {
    int wid = (blockIdx.x * blockDim.x + threadIdx.x) >> 6;
    int lane = threadIdx.x & 63;
    if (wid >= n) return;
    int beg = row_ptr[wid], end = row_ptr[wid + 1];
    float acc = 0.f;
    for (int j = beg; j < end; ++j) {
        int s = col[j];
        acc += h[(size_t)s * DIM + lane];
    }
    float c = (float)(end - beg);
    agg[(size_t)wid * DIM + lane] = acc / fmaxf(c, 1.0f);
}

// ---------------- fused linear (agg@Wl + bl + h@Wr) + BN(eval) + ReLU ----------------

__global__ __launch_bounds__(256) void k_xform(const float* __restrict__ agg,
                                               const float* __restrict__ h,
                                               const float* __restrict__ Wl,
                                               const float* __restrict__ bl,
                                               const float* __restrict__ Wr,
                                               const float* __restrict__ bng,
                                               const float* __restrict__ bnb,
                                               const float* __restrict__ bnm,
                                               const float* __restrict__ bnv,
                                               float* __restrict__ out, int n) {
    __shared__ float sWl[64 * 64];
    __shared__ float sWr[64 * 64];
    __shared__ float sA[64 * 64];
    __shared__ float sH[64 * 64];
    int tid = threadIdx.x;
    int base = blockIdx.x * 64;
    int rows = min(64, n - base);

    const float4* Wl4 = (const float4*)Wl;
    const float4* Wr4 = (const float4*)Wr;
    float4* sWl4 = (float4*)sWl;
    float4* sWr4 = (float4*)sWr;
    const float4* A4 = (const float4*)(agg + (size_t)base * DIM);
    const float4* H4 = (const float4*)(h + (size_t)base * DIM);
    float4* sA4 = (float4*)sA;
    float4* sH4 = (float4*)sH;
    for (int i = tid; i < 64 * 64 / 4; i += 256) {
        sWl4[i] = Wl4[i];
        sWr4[i] = Wr4[i];
        int row = i >> 4;
        float4 va = {0.f, 0.f, 0.f, 0.f}, vh = {0.f, 0.f, 0.f, 0.f};
        if (row < rows) { va = A4[i]; vh = H4[i]; }
        sA4[i] = va;
        sH4[i] = vh;
    }
    __syncthreads();

    int d = tid & 63;
    int nq = tid >> 6;
    float acc[16];
#pragma unroll
    for (int i = 0; i < 16; ++i) acc[i] = 0.f;

    for (int k = 0; k < 64; k += 4) {
        float wl0 = sWl[(k + 0) * 64 + d];
        float wl1 = sWl[(k + 1) * 64 + d];
        float wl2 = sWl[(k + 2) * 64 + d];
        float wl3 = sWl[(k + 3) * 64 + d];
        float wr0 = sWr[(k + 0) * 64 + d];
        float wr1 = sWr[(k + 1) * 64 + d];
        float wr2 = sWr[(k + 2) * 64 + d];
        float wr3 = sWr[(k + 3) * 64 + d];
#pragma unroll
        for (int i = 0; i < 16; ++i) {
            int nd = nq + 4 * i;
            const float4 a4 = *(const float4*)&sA[nd * 64 + k];
            const float4 h4 = *(const float4*)&sH[nd * 64 + k];
            acc[i] += a4.x * wl0 + a4.y * wl1 + a4.z * wl2 + a4.w * wl3
                    + h4.x * wr0 + h4.y * wr1 + h4.z * wr2 + h4.w * wr3;
        }
    }

    float scale = bng[d] / sqrtf(bnv[d] + BN_EPS);
    float shift = bnb[d];
    float mean = bnm[d];
    float bias = bl[d];
#pragma unroll
    for (int i = 0; i < 16; ++i) {
        int nd = nq + 4 * i;
        int node = base + nd;
        if (node < n) {
            float v = (acc[i] + bias - mean) * scale + shift;
            out[(size_t)node * DIM + d] = fmaxf(v, 0.f);
        }
    }
}

// ---------------- global mean pool (batch is sorted) ----------------

__global__ __launch_bounds__(256) void k_pool(const float* __restrict__ h,
                                              const int* __restrict__ batch,
                                              float* __restrict__ gsum,
                                              int* __restrict__ gcnt,
                                              int n, int npb) {
    __shared__ float ls[NGRAPH * DIM];
    __shared__ int lc[NGRAPH];
    int tid = threadIdx.x;
    for (int i = tid; i < NGRAPH * DIM; i += 256) ls[i] = 0.f;
    for (int i = tid; i < NGRAPH; i += 256) lc[i] = 0;
    __syncthreads();
    int start = blockIdx.x * npb;
    int end = min(start + npb, n);
    int lane = tid & 63, wv = tid >> 6;
    for (int i = start + wv; i < end; i += 4) {
        int g = batch[i];
        atomicAdd(&ls[g * DIM + lane], h[(size_t)i * DIM + lane]);
        if (lane == 0) atomicAdd(&lc[g], 1);
    }
    __syncthreads();
    int gmin = batch[start];
    int gmax = batch[end - 1];
    int span = gmax - gmin + 1;
    for (int i = tid; i < span * DIM; i += 256)
        atomicAdd(&gsum[gmin * DIM + i], ls[gmin * DIM + i]);
    for (int i = tid; i < span; i += 256)
        atomicAdd(&gcnt[gmin + i], lc[gmin + i]);
}

// ---------------- classifier head ----------------

__global__ __launch_bounds__(256) void k_mlp(const float* __restrict__ gsum,
                                             const int* __restrict__ gcnt,
                                             const float* __restrict__ gattr,
                                             const float* __restrict__ W1,
                                             const float* __restrict__ b1,
                                             const float* __restrict__ W2,
                                             const float* __restrict__ b2,
                                             float* __restrict__ out) {
    __shared__ float emb[NGRAPH][DIM + GATTR];
    __shared__ float hid[NGRAPH][32];
    int tid = threadIdx.x;
    for (int i = tid; i < NGRAPH * DIM; i += 256) {
        int g = i >> 6, d = i & 63;
        float c = (float)gcnt[g];
        emb[g][d] = gsum[i] / fmaxf(c, 1.0f);
    }
    for (int i = tid; i < NGRAPH * GATTR; i += 256) {
        int g = i >> 2, d = i & 3;
        emb[g][DIM + d] = gattr[i];
    }
    __syncthreads();
    for (int t = tid; t < NGRAPH * 32; t += 256) {
        int g = t >> 5, j = t & 31;
        float a = b1[j];
        for (int k = 0; k < DIM + GATTR; ++k) a += emb[g][k] * W1[k * 32 + j];
        hid[g][j] = fmaxf(a, 0.f);
    }
    __syncthreads();
    {
        int g = tid >> 1, o = tid & 1;
        float a = b2[o];
        for (int k = 0; k < 32; ++k) a += hid[g][k] * W2[k * 2 + o];
        out[g * 2 + o] = a;
    }
}

extern "C" void kernel_launch(void* const* d_in, const int* in_sizes, int n_in,
                              void* d_out, int out_size, void* d_ws, size_t ws_size,
                              hipStream_t stream) {
    const float* x = (const float*)d_in[0];
    const int* ei = (const int*)d_in[1];
    const int* batch = (const int*)d_in[2];
    const float* gattr = (const float*)d_in[3];
    const int N = in_sizes[0] / DIM;
    const int E = in_sizes[1] / 2;
    const int* src = ei;
    const int* dst = ei + E;

    const float *Wl[3], *bl[3], *Wr[3], *bg[3], *bb[3], *bm[3], *bv[3];
    for (int l = 0; l < 3; ++l) {
        int base = 4 + l * 7;
        Wl[l] = (const float*)d_in[base + 0];
        bl[l] = (const float*)d_in[base + 1];
        Wr[l] = (const float*)d_in[base + 2];
        bg[l] = (const float*)d_in[base + 3];
        bb[l] = (const float*)d_in[base + 4];
        bm[l] = (const float*)d_in[base + 5];
        bv[l] = (const float*)d_in[base + 6];
    }
    const float* W1 = (const float*)d_in[25];
    const float* b1 = (const float*)d_in[26];
    const float* W2 = (const float*)d_in[27];
    const float* b2 = (const float*)d_in[28];

    char* ws = (char*)d_ws;
    size_t off = 0;
    auto alloc = [&](size_t bytes) -> char* {
        char* p = ws + off;
        off += (bytes + 255) & ~(size_t)255;
        return p;
    };
    int* cnt = (int*)alloc((size_t)N * 4);
    int* rowptr = (int*)alloc((size_t)(N + 1) * 4);
    int* wp = (int*)alloc((size_t)N * 4);
    int* col = (int*)alloc((size_t)E * 4);
    float* aggb = (float*)alloc((size_t)N * DIM * 4);
    float* h0 = (float*)alloc((size_t)N * DIM * 4);
    float* h1 = (float*)alloc((size_t)N * DIM * 4);
    float* gsum = (float*)alloc((size_t)NGRAPH * DIM * 4);
    int* gcnt = (int*)alloc((size_t)NGRAPH * 4);
    int* partials = (int*)alloc(1024 * 4);
    (void)ws_size;

    hipMemsetAsync(cnt, 0, (size_t)N * 4, stream);
    hipMemsetAsync(gsum, 0, (size_t)NGRAPH * DIM * 4, stream);
    hipMemsetAsync(gcnt, 0, (size_t)NGRAPH * 4, stream);

    const int tpb = 256;
    const int nscan = (N + SCAN_CHUNK - 1) / SCAN_CHUNK;
    k_count<<<(E + tpb - 1) / tpb, tpb, 0, stream>>>(dst, cnt, E);
    k_scan1<<<nscan, tpb, 0, stream>>>(cnt, rowptr, partials, N);
    k_scan2<<<1, tpb, 0, stream>>>(partials, nscan);
    k_scan3<<<nscan, tpb, 0, stream>>>(rowptr, wp, partials, N, E);
    k_scatter<<<(E + tpb - 1) / tpb, tpb, 0, stream>>>(src, dst, wp, col, E);

    const float* hin = x;
    float* houts[3] = {h0, h1, h0};
    for (int l = 0; l < 3; ++l) {
        k_agg<<<(N * 64 + tpb - 1) / tpb, tpb, 0, stream>>>(hin, rowptr, col, aggb, N);
        k_xform<<<(N + 63) / 64, 256, 0, stream>>>(aggb, hin, Wl[l], bl[l], Wr[l],
                                                   bg[l], bb[l], bm[l], bv[l], houts[l], N);
        hin = houts[l];
    }

    const int NPB = 1024;
    k_pool<<<(N + NPB - 1) / NPB, tpb, 0, stream>>>(hin, batch, gsum, gcnt, N, NPB);
    k_mlp<<<1, tpb, 0, stream>>>(gsum, gcnt, gattr, W1, b1, W2, b2, (float*)d_out);
}

// Round 4
// 672.900 us; speedup vs baseline: 1.6502x; 1.3093x over previous
//
#include <hip/hip_runtime.h>

#define DIM 64
#define NGRAPH 128
#define GATTR 4
#define BN_EPS 1e-5f
#define SCAN_CHUNK 4096  // 256 threads x 16 elems

// ---------------- CSR build ----------------

__global__ void k_count(const int* __restrict__ dst, int* __restrict__ cnt, int E) {
    int e = blockIdx.x * blockDim.x + threadIdx.x;
    if (e < E) atomicAdd(&cnt[dst[e]], 1);
}

// Stage 1: per-block local exclusive scan (4096 elems) + block total
__global__ __launch_bounds__(256) void k_scan1(const int* __restrict__ cnt,
                                               int* __restrict__ rowptr,
                                               int* __restrict__ partials, int n) {
    __shared__ int ws[256];
    int tid = threadIdx.x;
    int base = blockIdx.x * SCAN_CHUNK + tid * 16;
    int v[16];
    int s = 0;
#pragma unroll
    for (int i = 0; i < 16; ++i) {
        int idx = base + i;
        v[i] = (idx < n) ? cnt[idx] : 0;
        s += v[i];
    }
    ws[tid] = s;
    __syncthreads();
    for (int off = 1; off < 256; off <<= 1) {
        int t = (tid >= off) ? ws[tid - off] : 0;
        __syncthreads();
        ws[tid] += t;
        __syncthreads();
    }
    int excl = (tid == 0) ? 0 : ws[tid - 1];
    if (tid == 255) partials[blockIdx.x] = ws[255];
#pragma unroll
    for (int i = 0; i < 16; ++i) {
        int idx = base + i;
        if (idx < n) rowptr[idx] = excl;
        excl += v[i];
    }
}

// Stage 2: exclusive scan of block totals (nb <= 256)
__global__ __launch_bounds__(256) void k_scan2(int* __restrict__ partials, int nb) {
    __shared__ int ws[256];
    int tid = threadIdx.x;
    int orig = (tid < nb) ? partials[tid] : 0;
    ws[tid] = orig;
    __syncthreads();
    for (int off = 1; off < 256; off <<= 1) {
        int t = (tid >= off) ? ws[tid - off] : 0;
        __syncthreads();
        ws[tid] += t;
        __syncthreads();
    }
    if (tid < nb) partials[tid] = ws[tid] - orig;  // exclusive
}

// Stage 3: add block offsets, fan out to rowptr and wp
__global__ __launch_bounds__(256) void k_scan3(int* __restrict__ rowptr,
                                               int* __restrict__ wp,
                                               const int* __restrict__ partials,
                                               int n, int E) {
    int base = blockIdx.x * SCAN_CHUNK;
    int off = partials[blockIdx.x];
    for (int i = threadIdx.x; i < SCAN_CHUNK; i += 256) {
        int idx = base + i;
        if (idx < n) {
            int v = rowptr[idx] + off;
            rowptr[idx] = v;
            wp[idx] = v;
        }
    }
    if (blockIdx.x == 0 && threadIdx.x == 0) rowptr[n] = E;
}

__global__ void k_scatter(const int* __restrict__ src, const int* __restrict__ dst,
                          int* __restrict__ wp, int* __restrict__ col, int E) {
    int e = blockIdx.x * blockDim.x + threadIdx.x;
    if (e < E) {
        int p = atomicAdd(&wp[dst[e]], 1);
        col[p] = src[e];
    }
}

// ---------------- mean aggregation ----------------
// One wave per node. lane = (g, p): g = edge slot (0..3), p = dim quad (0..15).
// Each lane loads float4 -> one instruction gathers 4 rows (1 KiB/wave);
// unroll x2 -> 8 independent gathers in flight. Reduce across g via shfl_xor.

__global__ __launch_bounds__(256) void k_agg(const float* __restrict__ h,
                                             const int* __restrict__ row_ptr,
                                             const int* __restrict__ col,
                                             float* __restrict__ agg, int n) {
    int wid = (blockIdx.x * blockDim.x + threadIdx.x) >> 6;
    if (wid >= n) return;
    int lane = threadIdx.x & 63;
    int g = lane >> 4;   // edge slot
    int p = lane & 15;   // dim quad: dims 4p..4p+3
    int beg = row_ptr[wid], end = row_ptr[wid + 1];

    float ax = 0.f, ay = 0.f, az = 0.f, aw = 0.f;
    float bx = 0.f, by = 0.f, bz = 0.f, bw = 0.f;
    int j = beg + g;
    for (; j + 4 < end; j += 8) {
        int s0 = col[j];
        int s1 = col[j + 4];
        float4 v0 = ((const float4*)(h + (size_t)s0 * DIM))[p];
        float4 v1 = ((const float4*)(h + (size_t)s1 * DIM))[p];
        ax += v0.x; ay += v0.y; az += v0.z; aw += v0.w;
        bx += v1.x; by += v1.y; bz += v1.z; bw += v1.w;
    }
    if (j < end) {
        int s0 = col[j];
        float4 v0 = ((const float4*)(h + (size_t)s0 * DIM))[p];
        ax += v0.x; ay += v0.y; az += v0.z; aw += v0.w;
    }
    ax += bx; ay += by; az += bz; aw += bw;

    // reduce across the 4 edge slots (lanes differing in bits 4,5)
#pragma unroll
    for (int m = 16; m <= 32; m <<= 1) {
        ax += __shfl_xor(ax, m, 64);
        ay += __shfl_xor(ay, m, 64);
        az += __shfl_xor(az, m, 64);
        aw += __shfl_xor(aw, m, 64);
    }

    if (g == 0) {
        float c = (float)(end - beg);
        float inv = 1.0f / fmaxf(c, 1.0f);
        float4 r;
        r.x = ax * inv; r.y = ay * inv; r.z = az * inv; r.w = aw * inv;
        ((float4*)(agg + (size_t)wid * DIM))[p] = r;
    }
}

// ---------------- fused linear (agg@Wl + bl + h@Wr) + BN(eval) + ReLU ----------------

__global__ __launch_bounds__(256) void k_xform(const float* __restrict__ agg,
                                               const float* __restrict__ h,
                                               const float* __restrict__ Wl,
                                               const float* __restrict__ bl,
                                               const float* __restrict__ Wr,
                                               const float* __restrict__ bng,
                                               const float* __restrict__ bnb,
                                               const float* __restrict__ bnm,
                                               const float* __restrict__ bnv,
                                               float* __restrict__ out, int n) {
    __shared__ float sWl[64 * 64];
    __shared__ float sWr[64 * 64];
    __shared__ float sA[64 * 64];
    __shared__ float sH[64 * 64];
    int tid = threadIdx.x;
    int base = blockIdx.x * 64;
    int rows = min(64, n - base);

    const float4* Wl4 = (const float4*)Wl;
    const float4* Wr4 = (const float4*)Wr;
    float4* sWl4 = (float4*)sWl;
    float4* sWr4 = (float4*)sWr;
    const float4* A4 = (const float4*)(agg + (size_t)base * DIM);
    const float4* H4 = (const float4*)(h + (size_t)base * DIM);
    float4* sA4 = (float4*)sA;
    float4* sH4 = (float4*)sH;
    for (int i = tid; i < 64 * 64 / 4; i += 256) {
        sWl4[i] = Wl4[i];
        sWr4[i] = Wr4[i];
        int row = i >> 4;
        float4 va = {0.f, 0.f, 0.f, 0.f}, vh = {0.f, 0.f, 0.f, 0.f};
        if (row < rows) { va = A4[i]; vh = H4[i]; }
        sA4[i] = va;
        sH4[i] = vh;
    }
    __syncthreads();

    int d = tid & 63;
    int nq = tid >> 6;
    float acc[16];
#pragma unroll
    for (int i = 0; i < 16; ++i) acc[i] = 0.f;

    for (int k = 0; k < 64; k += 4) {
        float wl0 = sWl[(k + 0) * 64 + d];
        float wl1 = sWl[(k + 1) * 64 + d];
        float wl2 = sWl[(k + 2) * 64 + d];
        float wl3 = sWl[(k + 3) * 64 + d];
        float wr0 = sWr[(k + 0) * 64 + d];
        float wr1 = sWr[(k + 1) * 64 + d];
        float wr2 = sWr[(k + 2) * 64 + d];
        float wr3 = sWr[(k + 3) * 64 + d];
#pragma unroll
        for (int i = 0; i < 16; ++i) {
            int nd = nq + 4 * i;
            const float4 a4 = *(const float4*)&sA[nd * 64 + k];
            const float4 h4 = *(const float4*)&sH[nd * 64 + k];
            acc[i] += a4.x * wl0 + a4.y * wl1 + a4.z * wl2 + a4.w * wl3
                    + h4.x * wr0 + h4.y * wr1 + h4.z * wr2 + h4.w * wr3;
        }
    }

    float scale = bng[d] / sqrtf(bnv[d] + BN_EPS);
    float shift = bnb[d];
    float mean = bnm[d];
    float bias = bl[d];
#pragma unroll
    for (int i = 0; i < 16; ++i) {
        int nd = nq + 4 * i;
        int node = base + nd;
        if (node < n) {
            float v = (acc[i] + bias - mean) * scale + shift;
            out[(size_t)node * DIM + d] = fmaxf(v, 0.f);
        }
    }
}

// ---------------- global mean pool (batch is sorted) ----------------

__global__ __launch_bounds__(256) void k_pool(const float* __restrict__ h,
                                              const int* __restrict__ batch,
                                              float* __restrict__ gsum,
                                              int* __restrict__ gcnt,
                                              int n, int npb) {
    __shared__ float ls[NGRAPH * DIM];
    __shared__ int lc[NGRAPH];
    int tid = threadIdx.x;
    for (int i = tid; i < NGRAPH * DIM; i += 256) ls[i] = 0.f;
    for (int i = tid; i < NGRAPH; i += 256) lc[i] = 0;
    __syncthreads();
    int start = blockIdx.x * npb;
    int end = min(start + npb, n);
    int lane = tid & 63, wv = tid >> 6;
    for (int i = start + wv; i < end; i += 4) {
        int g = batch[i];
        atomicAdd(&ls[g * DIM + lane], h[(size_t)i * DIM + lane]);
        if (lane == 0) atomicAdd(&lc[g], 1);
    }
    __syncthreads();
    int gmin = batch[start];
    int gmax = batch[end - 1];
    int span = gmax - gmin + 1;
    for (int i = tid; i < span * DIM; i += 256)
        atomicAdd(&gsum[gmin * DIM + i], ls[gmin * DIM + i]);
    for (int i = tid; i < span; i += 256)
        atomicAdd(&gcnt[gmin + i], lc[gmin + i]);
}

// ---------------- classifier head ----------------

__global__ __launch_bounds__(256) void k_mlp(const float* __restrict__ gsum,
                                             const int* __restrict__ gcnt,
                                             const float* __restrict__ gattr,
                                             const float* __restrict__ W1,
                                             const float* __restrict__ b1,
                                             const float* __restrict__ W2,
                                             const float* __restrict__ b2,
                                             float* __restrict__ out) {
    __shared__ float emb[NGRAPH][DIM + GATTR];
    __shared__ float hid[NGRAPH][32];
    int tid = threadIdx.x;
    for (int i = tid; i < NGRAPH * DIM; i += 256) {
        int g = i >> 6, d = i & 63;
        float c = (float)gcnt[g];
        emb[g][d] = gsum[i] / fmaxf(c, 1.0f);
    }
    for (int i = tid; i < NGRAPH * GATTR; i += 256) {
        int g = i >> 2, d = i & 3;
        emb[g][DIM + d] = gattr[i];
    }
    __syncthreads();
    for (int t = tid; t < NGRAPH * 32; t += 256) {
        int g = t >> 5, j = t & 31;
        float a = b1[j];
        for (int k = 0; k < DIM + GATTR; ++k) a += emb[g][k] * W1[k * 32 + j];
        hid[g][j] = fmaxf(a, 0.f);
    }
    __syncthreads();
    {
        int g = tid >> 1, o = tid & 1;
        float a = b2[o];
        for (int k = 0; k < 32; ++k) a += hid[g][k] * W2[k * 2 + o];
        out[g * 2 + o] = a;
    }
}

extern "C" void kernel_launch(void* const* d_in, const int* in_sizes, int n_in,
                              void* d_out, int out_size, void* d_ws, size_t ws_size,
                              hipStream_t stream) {
    const float* x = (const float*)d_in[0];
    const int* ei = (const int*)d_in[1];
    const int* batch = (const int*)d_in[2];
    const float* gattr = (const float*)d_in[3];
    const int N = in_sizes[0] / DIM;
    const int E = in_sizes[1] / 2;
    const int* src = ei;
    const int* dst = ei + E;

    const float *Wl[3], *bl[3], *Wr[3], *bg[3], *bb[3], *bm[3], *bv[3];
    for (int l = 0; l < 3; ++l) {
        int base = 4 + l * 7;
        Wl[l] = (const float*)d_in[base + 0];
        bl[l] = (const float*)d_in[base + 1];
        Wr[l] = (const float*)d_in[base + 2];
        bg[l] = (const float*)d_in[base + 3];
        bb[l] = (const float*)d_in[base + 4];
        bm[l] = (const float*)d_in[base + 5];
        bv[l] = (const float*)d_in[base + 6];
    }
    const float* W1 = (const float*)d_in[25];
    const float* b1 = (const float*)d_in[26];
    const float* W2 = (const float*)d_in[27];
    const float* b2 = (const float*)d_in[28];

    char* ws = (char*)d_ws;
    size_t off = 0;
    auto alloc = [&](size_t bytes) -> char* {
        char* p = ws + off;
        off += (bytes + 255) & ~(size_t)255;
        return p;
    };
    int* cnt = (int*)alloc((size_t)N * 4);
    int* rowptr = (int*)alloc((size_t)(N + 1) * 4);
    int* wp = (int*)alloc((size_t)N * 4);
    int* col = (int*)alloc((size_t)E * 4);
    float* aggb = (float*)alloc((size_t)N * DIM * 4);
    float* h0 = (float*)alloc((size_t)N * DIM * 4);
    float* h1 = (float*)alloc((size_t)N * DIM * 4);
    float* gsum = (float*)alloc((size_t)NGRAPH * DIM * 4);
    int* gcnt = (int*)alloc((size_t)NGRAPH * 4);
    int* partials = (int*)alloc(1024 * 4);
    (void)ws_size;

    hipMemsetAsync(cnt, 0, (size_t)N * 4, stream);
    hipMemsetAsync(gsum, 0, (size_t)NGRAPH * DIM * 4, stream);
    hipMemsetAsync(gcnt, 0, (size_t)NGRAPH * 4, stream);

    const int tpb = 256;
    const int nscan = (N + SCAN_CHUNK - 1) / SCAN_CHUNK;
    k_count<<<(E + tpb - 1) / tpb, tpb, 0, stream>>>(dst, cnt, E);
    k_scan1<<<nscan, tpb, 0, stream>>>(cnt, rowptr, partials, N);
    k_scan2<<<1, tpb, 0, stream>>>(partials, nscan);
    k_scan3<<<nscan, tpb, 0, stream>>>(rowptr, wp, partials, N, E);
    k_scatter<<<(E + tpb - 1) / tpb, tpb, 0, stream>>>(src, dst, wp, col, E);

    const float* hin = x;
    float* houts[3] = {h0, h1, h0};
    for (int l = 0; l < 3; ++l) {
        k_agg<<<(N * 64 + tpb - 1) / tpb, tpb, 0, stream>>>(hin, rowptr, col, aggb, N);
        k_xform<<<(N + 63) / 64, 256, 0, stream>>>(aggb, hin, Wl[l], bl[l], Wr[l],
                                                   bg[l], bb[l], bm[l], bv[l], houts[l], N);
        hin = houts[l];
    }

    const int NPB = 1024;
    k_pool<<<(N + NPB - 1) / NPB, tpb, 0, stream>>>(hin, batch, gsum, gcnt, N, NPB);
    k_mlp<<<1, tpb, 0, stream>>>(gsum, gcnt, gattr, W1, b1, W2, b2, (float*)d_out);
}

// Round 5
// 651.717 us; speedup vs baseline: 1.7039x; 1.0325x over previous
//
#include <hip/hip_runtime.h>

#define DIM 64
#define NGRAPH 128
#define GATTR 4
#define BN_EPS 1e-5f
#define SCAN_CHUNK 4096  // 256 threads x 16 elems

// ---------------- CSR build ----------------

__global__ __launch_bounds__(256) void k_count(const int* __restrict__ dst,
                                               int* __restrict__ cnt, int E) {
    int base = blockIdx.x * (blockDim.x * 8) + threadIdx.x;
#pragma unroll
    for (int i = 0; i < 8; ++i) {
        int e = base + i * 256;
        if (e < E) atomicAdd(&cnt[dst[e]], 1);
    }
}

// Stage 1: per-block local exclusive scan (4096 elems) + block total
__global__ __launch_bounds__(256) void k_scan1(const int* __restrict__ cnt,
                                               int* __restrict__ rowptr,
                                               int* __restrict__ partials, int n) {
    __shared__ int ws[256];
    int tid = threadIdx.x;
    int base = blockIdx.x * SCAN_CHUNK + tid * 16;
    int v[16];
    int s = 0;
#pragma unroll
    for (int i = 0; i < 16; ++i) {
        int idx = base + i;
        v[i] = (idx < n) ? cnt[idx] : 0;
        s += v[i];
    }
    ws[tid] = s;
    __syncthreads();
    for (int off = 1; off < 256; off <<= 1) {
        int t = (tid >= off) ? ws[tid - off] : 0;
        __syncthreads();
        ws[tid] += t;
        __syncthreads();
    }
    int excl = (tid == 0) ? 0 : ws[tid - 1];
    if (tid == 255) partials[blockIdx.x] = ws[255];
#pragma unroll
    for (int i = 0; i < 16; ++i) {
        int idx = base + i;
        if (idx < n) rowptr[idx] = excl;
        excl += v[i];
    }
}

// Stage 2: exclusive scan of block totals (nb <= 256)
__global__ __launch_bounds__(256) void k_scan2(int* __restrict__ partials, int nb) {
    __shared__ int ws[256];
    int tid = threadIdx.x;
    int orig = (tid < nb) ? partials[tid] : 0;
    ws[tid] = orig;
    __syncthreads();
    for (int off = 1; off < 256; off <<= 1) {
        int t = (tid >= off) ? ws[tid - off] : 0;
        __syncthreads();
        ws[tid] += t;
        __syncthreads();
    }
    if (tid < nb) partials[tid] = ws[tid] - orig;  // exclusive
}

// Stage 3: add block offsets, fan out to rowptr and wp
__global__ __launch_bounds__(256) void k_scan3(int* __restrict__ rowptr,
                                               int* __restrict__ wp,
                                               const int* __restrict__ partials,
                                               int n, int E) {
    int base = blockIdx.x * SCAN_CHUNK;
    int off = partials[blockIdx.x];
    for (int i = threadIdx.x; i < SCAN_CHUNK; i += 256) {
        int idx = base + i;
        if (idx < n) {
            int v = rowptr[idx] + off;
            rowptr[idx] = v;
            wp[idx] = v;
        }
    }
    if (blockIdx.x == 0 && threadIdx.x == 0) rowptr[n] = E;
}

__global__ __launch_bounds__(256) void k_scatter(const int* __restrict__ src,
                                                 const int* __restrict__ dst,
                                                 int* __restrict__ wp,
                                                 int* __restrict__ col, int E) {
    int base = blockIdx.x * (blockDim.x * 8) + threadIdx.x;
#pragma unroll
    for (int i = 0; i < 8; ++i) {
        int e = base + i * 256;
        if (e < E) {
            int p = atomicAdd(&wp[dst[e]], 1);
            col[p] = src[e];
        }
    }
}

// ---------------- mean aggregation ----------------
// One wave per node. lane = (g, p): g = edge slot (0..3), p = dim quad (0..15).
// Each lane loads float4 -> one instruction gathers 4 rows (1 KiB/wave);
// unroll x2 -> 8 independent gathers in flight. Reduce across g via shfl_xor.

__global__ __launch_bounds__(256) void k_agg(const float* __restrict__ h,
                                             const int* __restrict__ row_ptr,
                                             const int* __restrict__ col,
                                             float* __restrict__ agg, int n) {
    int wid = (blockIdx.x * blockDim.x + threadIdx.x) >> 6;
    if (wid >= n) return;
    int lane = threadIdx.x & 63;
    int g = lane >> 4;   // edge slot
    int p = lane & 15;   // dim quad: dims 4p..4p+3
    int beg = row_ptr[wid], end = row_ptr[wid + 1];

    float ax = 0.f, ay = 0.f, az = 0.f, aw = 0.f;
    float bx = 0.f, by = 0.f, bz = 0.f, bw = 0.f;
    int j = beg + g;
    for (; j + 4 < end; j += 8) {
        int s0 = col[j];
        int s1 = col[j + 4];
        float4 v0 = ((const float4*)(h + (size_t)s0 * DIM))[p];
        float4 v1 = ((const float4*)(h + (size_t)s1 * DIM))[p];
        ax += v0.x; ay += v0.y; az += v0.z; aw += v0.w;
        bx += v1.x; by += v1.y; bz += v1.z; bw += v1.w;
    }
    if (j < end) {
        int s0 = col[j];
        float4 v0 = ((const float4*)(h + (size_t)s0 * DIM))[p];
        ax += v0.x; ay += v0.y; az += v0.z; aw += v0.w;
    }
    ax += bx; ay += by; az += bz; aw += bw;

    // reduce across the 4 edge slots (lanes differing in bits 4,5)
#pragma unroll
    for (int m = 16; m <= 32; m <<= 1) {
        ax += __shfl_xor(ax, m, 64);
        ay += __shfl_xor(ay, m, 64);
        az += __shfl_xor(az, m, 64);
        aw += __shfl_xor(aw, m, 64);
    }

    if (g == 0) {
        float c = (float)(end - beg);
        float inv = 1.0f / fmaxf(c, 1.0f);
        float4 r;
        r.x = ax * inv; r.y = ay * inv; r.z = az * inv; r.w = aw * inv;
        ((float4*)(agg + (size_t)wid * DIM))[p] = r;
    }
}

// ---------------- fused linear (agg@Wl + bl + h@Wr) + BN(eval) + ReLU ----------------

__global__ __launch_bounds__(256) void k_xform(const float* __restrict__ agg,
                                               const float* __restrict__ h,
                                               const float* __restrict__ Wl,
                                               const float* __restrict__ bl,
                                               const float* __restrict__ Wr,
                                               const float* __restrict__ bng,
                                               const float* __restrict__ bnb,
                                               const float* __restrict__ bnm,
                                               const float* __restrict__ bnv,
                                               float* __restrict__ out, int n) {
    __shared__ float sWl[64 * 64];
    __shared__ float sWr[64 * 64];
    __shared__ float sA[64 * 64];
    __shared__ float sH[64 * 64];
    int tid = threadIdx.x;
    int base = blockIdx.x * 64;
    int rows = min(64, n - base);

    const float4* Wl4 = (const float4*)Wl;
    const float4* Wr4 = (const float4*)Wr;
    float4* sWl4 = (float4*)sWl;
    float4* sWr4 = (float4*)sWr;
    const float4* A4 = (const float4*)(agg + (size_t)base * DIM);
    const float4* H4 = (const float4*)(h + (size_t)base * DIM);
    float4* sA4 = (float4*)sA;
    float4* sH4 = (float4*)sH;
    for (int i = tid; i < 64 * 64 / 4; i += 256) {
        sWl4[i] = Wl4[i];
        sWr4[i] = Wr4[i];
        int row = i >> 4;
        float4 va = {0.f, 0.f, 0.f, 0.f}, vh = {0.f, 0.f, 0.f, 0.f};
        if (row < rows) { va = A4[i]; vh = H4[i]; }
        sA4[i] = va;
        sH4[i] = vh;
    }
    __syncthreads();

    int d = tid & 63;
    int nq = tid >> 6;
    float acc[16];
#pragma unroll
    for (int i = 0; i < 16; ++i) acc[i] = 0.f;

    for (int k = 0; k < 64; k += 4) {
        float wl0 = sWl[(k + 0) * 64 + d];
        float wl1 = sWl[(k + 1) * 64 + d];
        float wl2 = sWl[(k + 2) * 64 + d];
        float wl3 = sWl[(k + 3) * 64 + d];
        float wr0 = sWr[(k + 0) * 64 + d];
        float wr1 = sWr[(k + 1) * 64 + d];
        float wr2 = sWr[(k + 2) * 64 + d];
        float wr3 = sWr[(k + 3) * 64 + d];
#pragma unroll
        for (int i = 0; i < 16; ++i) {
            int nd = nq + 4 * i;
            const float4 a4 = *(const float4*)&sA[nd * 64 + k];
            const float4 h4 = *(const float4*)&sH[nd * 64 + k];
            acc[i] += a4.x * wl0 + a4.y * wl1 + a4.z * wl2 + a4.w * wl3
                    + h4.x * wr0 + h4.y * wr1 + h4.z * wr2 + h4.w * wr3;
        }
    }

    float scale = bng[d] / sqrtf(bnv[d] + BN_EPS);
    float shift = bnb[d];
    float mean = bnm[d];
    float bias = bl[d];
#pragma unroll
    for (int i = 0; i < 16; ++i) {
        int nd = nq + 4 * i;
        int node = base + nd;
        if (node < n) {
            float v = (acc[i] + bias - mean) * scale + shift;
            out[(size_t)node * DIM + d] = fmaxf(v, 0.f);
        }
    }
}

// ---------------- global mean pool (batch sorted) ----------------
// One wave per contiguous node chunk; register accumulation while graph id
// (wave-uniform) is unchanged; flush to global atomics on change. ~1150
// flushes total across the grid.

__global__ __launch_bounds__(256) void k_pool(const float* __restrict__ h,
                                              const int* __restrict__ batch,
                                              float* __restrict__ gsum,
                                              int* __restrict__ gcnt, int n) {
    int nw = gridDim.x * 4;
    int w = blockIdx.x * 4 + (threadIdx.x >> 6);
    int lane = threadIdx.x & 63;
    int chunk = (n + nw - 1) / nw;
    int s = w * chunk, e = min(s + chunk, n);
    if (s >= e) return;
    int cur = batch[s];
    float acc = 0.f;
    int cnt = 0;
    for (int i = s; i < e; ++i) {
        int g = batch[i];
        if (g != cur) {
            atomicAdd(&gsum[cur * DIM + lane], acc);
            if (lane == 0) atomicAdd(&gcnt[cur], cnt);
            acc = 0.f; cnt = 0; cur = g;
        }
        acc += h[(size_t)i * DIM + lane];
        ++cnt;
    }
    atomicAdd(&gsum[cur * DIM + lane], acc);
    if (lane == 0) atomicAdd(&gcnt[cur], cnt);
}

// ---------------- classifier head ----------------

__global__ __launch_bounds__(256) void k_mlp(const float* __restrict__ gsum,
                                             const int* __restrict__ gcnt,
                                             const float* __restrict__ gattr,
                                             const float* __restrict__ W1,
                                             const float* __restrict__ b1,
                                             const float* __restrict__ W2,
                                             const float* __restrict__ b2,
                                             float* __restrict__ out) {
    __shared__ float emb[NGRAPH][DIM + GATTR];
    __shared__ float hid[NGRAPH][32];
    int tid = threadIdx.x;
    for (int i = tid; i < NGRAPH * DIM; i += 256) {
        int g = i >> 6, d = i & 63;
        float c = (float)gcnt[g];
        emb[g][d] = gsum[i] / fmaxf(c, 1.0f);
    }
    for (int i = tid; i < NGRAPH * GATTR; i += 256) {
        int g = i >> 2, d = i & 3;
        emb[g][DIM + d] = gattr[i];
    }
    __syncthreads();
    for (int t = tid; t < NGRAPH * 32; t += 256) {
        int g = t >> 5, j = t & 31;
        float a = b1[j];
        for (int k = 0; k < DIM + GATTR; ++k) a += emb[g][k] * W1[k * 32 + j];
        hid[g][j] = fmaxf(a, 0.f);
    }
    __syncthreads();
    {
        int g = tid >> 1, o = tid & 1;
        float a = b2[o];
        for (int k = 0; k < 32; ++k) a += hid[g][k] * W2[k * 2 + o];
        out[g * 2 + o] = a;
    }
}

extern "C" void kernel_launch(void* const* d_in, const int* in_sizes, int n_in,
                              void* d_out, int out_size, void* d_ws, size_t ws_size,
                              hipStream_t stream) {
    const float* x = (const float*)d_in[0];
    const int* ei = (const int*)d_in[1];
    const int* batch = (const int*)d_in[2];
    const float* gattr = (const float*)d_in[3];
    const int N = in_sizes[0] / DIM;
    const int E = in_sizes[1] / 2;
    const int* src = ei;
    const int* dst = ei + E;

    const float *Wl[3], *bl[3], *Wr[3], *bg[3], *bb[3], *bm[3], *bv[3];
    for (int l = 0; l < 3; ++l) {
        int base = 4 + l * 7;
        Wl[l] = (const float*)d_in[base + 0];
        bl[l] = (const float*)d_in[base + 1];
        Wr[l] = (const float*)d_in[base + 2];
        bg[l] = (const float*)d_in[base + 3];
        bb[l] = (const float*)d_in[base + 4];
        bm[l] = (const float*)d_in[base + 5];
        bv[l] = (const float*)d_in[base + 6];
    }
    const float* W1 = (const float*)d_in[25];
    const float* b1 = (const float*)d_in[26];
    const float* W2 = (const float*)d_in[27];
    const float* b2 = (const float*)d_in[28];

    char* ws = (char*)d_ws;
    size_t off = 0;
    auto alloc = [&](size_t bytes) -> char* {
        char* p = ws + off;
        off += (bytes + 255) & ~(size_t)255;
        return p;
    };
    int* cnt = (int*)alloc((size_t)N * 4);
    int* rowptr = (int*)alloc((size_t)(N + 1) * 4);
    int* wp = (int*)alloc((size_t)N * 4);
    int* col = (int*)alloc((size_t)E * 4);
    float* aggb = (float*)alloc((size_t)N * DIM * 4);
    float* h0 = (float*)alloc((size_t)N * DIM * 4);
    float* h1 = (float*)alloc((size_t)N * DIM * 4);
    float* gsum = (float*)alloc((size_t)NGRAPH * DIM * 4);
    int* gcnt = (int*)alloc((size_t)NGRAPH * 4);
    int* partials = (int*)alloc(1024 * 4);
    (void)ws_size;

    hipMemsetAsync(cnt, 0, (size_t)N * 4, stream);
    hipMemsetAsync(gsum, 0, (size_t)NGRAPH * DIM * 4, stream);
    hipMemsetAsync(gcnt, 0, (size_t)NGRAPH * 4, stream);

    const int tpb = 256;
    const int nscan = (N + SCAN_CHUNK - 1) / SCAN_CHUNK;
    const int nb8 = (E + tpb * 8 - 1) / (tpb * 8);
    k_count<<<nb8, tpb, 0, stream>>>(dst, cnt, E);
    k_scan1<<<nscan, tpb, 0, stream>>>(cnt, rowptr, partials, N);
    k_scan2<<<1, tpb, 0, stream>>>(partials, nscan);
    k_scan3<<<nscan, tpb, 0, stream>>>(rowptr, wp, partials, N, E);
    k_scatter<<<nb8, tpb, 0, stream>>>(src, dst, wp, col, E);

    const float* hin = x;
    float* houts[3] = {h0, h1, h0};
    for (int l = 0; l < 3; ++l) {
        k_agg<<<(N * 64 + tpb - 1) / tpb, tpb, 0, stream>>>(hin, rowptr, col, aggb, N);
        k_xform<<<(N + 63) / 64, 256, 0, stream>>>(aggb, hin, Wl[l], bl[l], Wr[l],
                                                   bg[l], bb[l], bm[l], bv[l], houts[l], N);
        hin = houts[l];
    }

    k_pool<<<256, tpb, 0, stream>>>(hin, batch, gsum, gcnt, N);
    k_mlp<<<1, tpb, 0, stream>>>(gsum, gcnt, gattr, W1, b1, W2, b2, (float*)d_out);
}